// Round 11
// baseline (38.132 us; speedup 1.0000x reference)
//
#include <hip/hip_runtime.h>
#include <hip/hip_fp16.h>
#include <math.h>

#define D 40
#define NN 1024
#define BB 2
#define RH 20   // uints (half2 pairs) per row: 40 fp16 = 80 B

typedef __attribute__((ext_vector_type(8))) _Float16 f16x8;
typedef __attribute__((ext_vector_type(4))) float f32x4;

__device__ __forceinline__ unsigned int pk16(float a, float b) {
    return __builtin_bit_cast(unsigned int, __builtin_amdgcn_cvt_pkrtz(a, b));
}

// packed-fp16 gelu on a half2 pair: g = s - s/(exp2(s*(c1*s^2+c0))+1)
// overflow: exp2->inf -> r=0 -> g=s (correct); underflow: exp2->0 -> r=1 -> g=0 (correct)
__device__ __forceinline__ unsigned int gelu2u(unsigned int a_u, unsigned int x_u) {
    __half2 a = __builtin_bit_cast(__half2, a_u);
    __half2 x = __builtin_bit_cast(__half2, x_u);
    __half2 s = __hadd2(a, x);
    __half2 u = __hmul2(s, s);
    __half2 t1 = __hfma2(__float2half2_rn(0.10294366f), u,
                         __float2half2_rn(2.3022083f));
    __half2 z = __hmul2(s, t1);
    __half2 e = h2exp2(z);
    __half2 r = h2rcp(__hadd2(e, __float2half2_rn(1.0f)));
    __half2 g = __hsub2(s, __hmul2(s, r));
    return __builtin_bit_cast(unsigned int, g);
}

// ai16 = half2(x @ W1[:D] + b1), aj16 = half2(x @ W1[D:]); block 0 packs W2^T frags
__global__ __launch_bounds__(64) void precompute_kernel(
    const float* __restrict__ x, const float* __restrict__ W1,
    const float* __restrict__ b1, const float* __restrict__ W2,
    unsigned int* __restrict__ ai16, unsigned int* __restrict__ aj16,
    uint4* __restrict__ w2fT) {
    int r = blockIdx.x;
    int t = threadIdx.x;
    __shared__ float xr[D], s1s[D], s2s[D];
    if (t < D) xr[t] = x[(size_t)r * D + t];
    __syncthreads();
    if (t < D) {
        float s1 = b1[t];
        float s2 = 0.0f;
#pragma unroll
        for (int k = 0; k < D; ++k) {
            float xv = xr[k];
            s1 = fmaf(xv, W1[k * D + t], s1);
            s2 = fmaf(xv, W1[(D + k) * D + t], s2);
        }
        s1s[t] = s1;
        s2s[t] = s2;
    }
    __syncthreads();
    if (t < RH) {
        ai16[(size_t)r * RH + t] = pk16(s1s[2 * t], s1s[2 * t + 1]);
        aj16[(size_t)r * RH + t] = pk16(s2s[2 * t], s2s[2 * t + 1]);
    }
    if (r == 0) {
        // A = W2^T: A[m=d, k] = W2[k][d]; lane: m = l&15, k = kt*32 + (l>>4)*8 + e
        const int lr = t & 15, lg = t >> 4;
#pragma unroll
        for (int mt = 0; mt < 3; ++mt)
#pragma unroll
            for (int kt = 0; kt < 2; ++kt) {
                unsigned int u[4];
#pragma unroll
                for (int pe = 0; pe < 4; ++pe) {
                    int k0 = kt * 32 + lg * 8 + pe * 2;
                    int dd = mt * 16 + lr;
                    float v0 = (k0 < D && dd < D) ? W2[k0 * D + dd] : 0.0f;
                    float v1 = (k0 + 1 < D && dd < D) ? W2[(k0 + 1) * D + dd] : 0.0f;
                    u[pe] = pk16(v0, v1);
                }
                w2fT[(mt * 2 + kt) * 64 + t] = make_uint4(u[0], u[1], u[2], u[3]);
            }
    }
}

__global__ __launch_bounds__(256) void pair_kernel(
    const unsigned int* __restrict__ ai16, const unsigned int* __restrict__ aj16,
    const uint4* __restrict__ w2fT, const float* __restrict__ b2,
    float* __restrict__ out) {
    __shared__ float mbuf[224];               // 4 waves x 56 (only LDS use)

    const int t = threadIdx.x;
    const int bid = blockIdx.x;
    const int bb = bid & 1;
    const int i = NN - 1 - (bid >> 1);        // big rows first
    const int w = t >> 6;
    const int l = t & 63;
    const int lr = l & 15;
    const int lg = l >> 4;                    // 0..3

    // W2^T A-fragments (zero rows for k>=40 kill don't-care B slots)
    f16x8 w2t[3][2];
#pragma unroll
    for (int mt = 0; mt < 3; ++mt)
#pragma unroll
        for (int kt = 0; kt < 2; ++kt)
            w2t[mt][kt] = __builtin_bit_cast(f16x8, w2fT[(mt * 2 + kt) * 64 + l]);

    // bias for d = mt*16 + lg*4 + r (0 for d >= 40)
    float bv2[3][4];
#pragma unroll
    for (int mt = 0; mt < 3; ++mt)
#pragma unroll
        for (int r = 0; r < 4; ++r) {
            int d = mt * 16 + lg * 4 + r;
            bv2[mt][r] = (d < D) ? b2[d] : 0.0f;
        }

    // ai half2 quads: phase-A (k = 8lg..8lg+7) and tail (k = 32..39)
    const unsigned int* ai_row = ai16 + ((size_t)bb * NN + i) * RH;
    const uint4 aiA = *reinterpret_cast<const uint4*>(ai_row + 4 * lg);
    const uint4 aiT = *reinterpret_cast<const uint4*>(ai_row + 16);
    const unsigned int* aj_b = aj16 + (size_t)bb * NN * RH;

    // per-lane softmax state (defer-rescale THR=8), merged in epilogue
    float m_run = 0.0f, l_run = 0.0f;
    float o[3][4];
#pragma unroll
    for (int mt = 0; mt < 3; ++mt)
#pragma unroll
        for (int r = 0; r < 4; ++r) o[mt][r] = 0.0f;

    // 64-j windows per wave, stride 256
    for (int jbase = w << 6; jbase <= i; jbase += 256) {
        // ---- loads: 4 phase-A quads + 1 tail quad (all half2, clamped rows) ----
        uint4 ajA[4], ajT;
#pragma unroll
        for (int n = 0; n < 4; ++n) {
            const int j0 = min(jbase + n * 16 + lr, i);
            ajA[n] = *reinterpret_cast<const uint4*>(aj_b + (size_t)j0 * RH + 4 * lg);
        }
        {
            const int jt = min(jbase + l, i);
            ajT = *reinterpret_cast<const uint4*>(aj_b + (size_t)jt * RH + 16);
        }

        // ---- tail gelu: k=32..39 of j=jbase+l (4 half2) ----
        unsigned int pd0 = gelu2u(aiT.x, ajT.x);
        unsigned int pd1 = gelu2u(aiT.y, ajT.y);
        unsigned int pd2 = gelu2u(aiT.z, ajT.z);
        unsigned int pd3 = gelu2u(aiT.w, ajT.w);

        f32x4 acc[3][4];
#pragma unroll
        for (int mt = 0; mt < 3; ++mt)
#pragma unroll
            for (int n = 0; n < 4; ++n)
                acc[mt][n] = (f32x4){bv2[mt][0], bv2[mt][1], bv2[mt][2], bv2[mt][3]};

#pragma unroll
        for (int n = 0; n < 4; ++n) {
            // phase-A fragment: gelu on this lane's k-quad of row j=16n+lr
            uint4 Bu;
            Bu.x = gelu2u(aiA.x, ajA[n].x);
            Bu.y = gelu2u(aiA.y, ajA[n].y);
            Bu.z = gelu2u(aiA.z, ajA[n].z);
            Bu.w = gelu2u(aiA.w, ajA[n].w);
            f16x8 B = __builtin_bit_cast(f16x8, Bu);
            // kt=1 fragment via bpermute from lane 16n+lr (k=32..39 pairs)
            const int idx = (lr << 2) + (n << 6);
            uint4 Tu;
            Tu.x = __builtin_amdgcn_ds_bpermute(idx, pd0);
            Tu.y = __builtin_amdgcn_ds_bpermute(idx, pd1);
            Tu.z = __builtin_amdgcn_ds_bpermute(idx, pd2);
            Tu.w = __builtin_amdgcn_ds_bpermute(idx, pd3);
            f16x8 Bt = __builtin_bit_cast(f16x8, Tu);
#pragma unroll
            for (int mt = 0; mt < 3; ++mt) {
                acc[mt][n] = __builtin_amdgcn_mfma_f32_16x16x32_f16(
                    w2t[mt][0], B, acc[mt][n], 0, 0, 0);
                acc[mt][n] = __builtin_amdgcn_mfma_f32_16x16x32_f16(
                    w2t[mt][1], Bt, acc[mt][n], 0, 0, 0);
            }
        }

        // ---- ||p|| per j; per-lane online softmax, defer-rescale (THR=8) ----
        float sv[4];
#pragma unroll
        for (int n = 0; n < 4; ++n) {
            float sq = 0.0f;
#pragma unroll
            for (int mt = 0; mt < 3; ++mt)
#pragma unroll
                for (int r = 0; r < 4; ++r)
                    sq = fmaf(acc[mt][n][r], acc[mt][n][r], sq);
            sq += __shfl_xor(sq, 16);
            sq += __shfl_xor(sq, 32);
            int j = jbase + n * 16 + lr;
            sv[n] = (j <= i) ? __builtin_amdgcn_sqrtf(sq) : -1e30f;
        }
        float mx = fmaxf(fmaxf(sv[0], sv[1]), fmaxf(sv[2], sv[3]));
        if (mx > m_run + 8.0f) {               // rare: keeps weights <= e^8
            float scale = __expf(m_run - mx);
            l_run *= scale;
#pragma unroll
            for (int mt = 0; mt < 3; ++mt)
#pragma unroll
                for (int r = 0; r < 4; ++r) o[mt][r] *= scale;
            m_run = mx;
        }
        float w0 = __expf(sv[0] - m_run);      // masked j -> exactly 0
        float w1 = __expf(sv[1] - m_run);
        float w2 = __expf(sv[2] - m_run);
        float w3 = __expf(sv[3] - m_run);
        l_run += (w0 + w1) + (w2 + w3);
#pragma unroll
        for (int mt = 0; mt < 3; ++mt)
#pragma unroll
            for (int r = 0; r < 4; ++r)
                o[mt][r] = fmaf(w0, acc[mt][0][r],
                           fmaf(w1, acc[mt][1][r],
                           fmaf(w2, acc[mt][2][r],
                           fmaf(w3, acc[mt][3][r], o[mt][r]))));
    }

    // ---- epilogue: per-lane -> wave max, rescale once, reduce, merge waves ----
    float M = m_run;
    M = fmaxf(M, __shfl_xor(M, 1));
    M = fmaxf(M, __shfl_xor(M, 2));
    M = fmaxf(M, __shfl_xor(M, 4));
    M = fmaxf(M, __shfl_xor(M, 8));
    float c0 = __expf(m_run - M);
    l_run *= c0;
#pragma unroll
    for (int mt = 0; mt < 3; ++mt)
#pragma unroll
        for (int r = 0; r < 4; ++r) {
            float v = o[mt][r] * c0;
            v += __shfl_xor(v, 1);
            v += __shfl_xor(v, 2);
            v += __shfl_xor(v, 4);
            v += __shfl_xor(v, 8);
            o[mt][r] = v;
        }
    l_run += __shfl_xor(l_run, 1);
    l_run += __shfl_xor(l_run, 2);
    l_run += __shfl_xor(l_run, 4);
    l_run += __shfl_xor(l_run, 8);

    if (lr == 0) {
#pragma unroll
        for (int mt = 0; mt < 3; ++mt)
#pragma unroll
            for (int r = 0; r < 4; ++r) {
                int d = mt * 16 + lg * 4 + r;
                if (d < D) mbuf[w * 56 + d] = o[mt][r];
            }
        if (lg == 0) { mbuf[w * 56 + 48] = l_run; mbuf[w * 56 + 49] = M; }
    }
    __syncthreads();
    if (t < D) {
        float Mg = fmaxf(fmaxf(mbuf[49], mbuf[56 + 49]),
                         fmaxf(mbuf[112 + 49], mbuf[168 + 49]));
        float L = 0.0f, val = 0.0f;
#pragma unroll
        for (int ww = 0; ww < 4; ++ww) {
            float c = __expf(mbuf[ww * 56 + 49] - Mg);
            L = fmaf(c, mbuf[ww * 56 + 48], L);
            val = fmaf(c, mbuf[ww * 56 + t], val);
        }
        out[((size_t)bb * NN + i) * D + t] = val / L;
    }
}

extern "C" void kernel_launch(void* const* d_in, const int* in_sizes, int n_in,
                              void* d_out, int out_size, void* d_ws, size_t ws_size,
                              hipStream_t stream) {
    const float* x  = (const float*)d_in[0];
    const float* W1 = (const float*)d_in[1];
    const float* b1 = (const float*)d_in[2];
    const float* W2 = (const float*)d_in[3];
    const float* b2 = (const float*)d_in[4];
    float* out = (float*)d_out;

    unsigned int* ai16 = (unsigned int*)d_ws;              // BB*NN*RH uints
    unsigned int* aj16 = ai16 + (size_t)BB * NN * RH;      // BB*NN*RH uints
    uint4* w2fT = (uint4*)(aj16 + (size_t)BB * NN * RH);   // 6*64 uint4

    precompute_kernel<<<BB * NN, 64, 0, stream>>>(x, W1, b1, W2, ai16, aj16, w2fT);
    pair_kernel<<<BB * NN, 256, 0, stream>>>(ai16, aj16, w2fT, b2, out);
}

// Round 12
// 34.903 us; speedup vs baseline: 1.0925x; 1.0925x over previous
//
#include <hip/hip_runtime.h>
#include <math.h>

#define D 40
#define NN 1024
#define BB 2

typedef __attribute__((ext_vector_type(8))) _Float16 f16x8;
typedef __attribute__((ext_vector_type(4))) float f32x4;

__device__ __forceinline__ unsigned int pk16(float a, float b) {
    return __builtin_bit_cast(unsigned int, __builtin_amdgcn_cvt_pkrtz(a, b));
}

// gelu = a - a/(exp2(a*(c1*a^2+c0))+1); 5 VALU + 2 trans
__device__ __forceinline__ float gelu_tanh(float a) {
    float u = a * a;
    float t1 = fmaf(0.10294366f, u, 2.3022083f);
    float e = __builtin_amdgcn_exp2f(a * t1);
    float r = __builtin_amdgcn_rcpf(e + 1.0f);
    return fmaf(-a, r, a);
}

// anti-remat pins
__device__ __forceinline__ void pinf(float& x) { asm volatile("" : "+v"(x)); }
__device__ __forceinline__ void pin4(float4& v) {
    asm volatile("" : "+v"(v.x), "+v"(v.y), "+v"(v.z), "+v"(v.w));
}
__device__ __forceinline__ void pin8(f16x8& v) {
    uint4 u = __builtin_bit_cast(uint4, v);
    asm volatile("" : "+v"(u.x), "+v"(u.y), "+v"(u.z), "+v"(u.w));
    v = __builtin_bit_cast(f16x8, u);
}

// build fp16x8 B-fragment: gelu(air + ajv) for 8 consecutive k
__device__ __forceinline__ f16x8 frag8(float4 a0, float4 a1, float4 x0, float4 x1) {
    float g0 = gelu_tanh(a0.x + x0.x);
    float g1 = gelu_tanh(a0.y + x0.y);
    float g2 = gelu_tanh(a0.z + x0.z);
    float g3 = gelu_tanh(a0.w + x0.w);
    float g4 = gelu_tanh(a1.x + x1.x);
    float g5 = gelu_tanh(a1.y + x1.y);
    float g6 = gelu_tanh(a1.z + x1.z);
    float g7 = gelu_tanh(a1.w + x1.w);
    return __builtin_bit_cast(f16x8,
        make_uint4(pk16(g0, g1), pk16(g2, g3), pk16(g4, g5), pk16(g6, g7)));
}

// ai = x @ W1[:D] + b1, aj = x @ W1[D:].  2 rows/block; one 40-FMA chain/thread.
// Block 0 threads 0..63 also pack the W2^T fp16 A-fragments.
__global__ __launch_bounds__(256) void precompute_kernel(
    const float* __restrict__ x, const float* __restrict__ W1,
    const float* __restrict__ b1, const float* __restrict__ W2,
    float* __restrict__ ai, float* __restrict__ aj, uint4* __restrict__ w2fT) {
    const int t = threadIdx.x;
    const int bid = blockIdx.x;
    const int r = (bid << 1) + (t >> 7);      // row (wave-uniform)
    const int tl = t & 127;
    const float* xr = x + (size_t)r * D;

    if (tl < D) {
        const int d = tl;
        float s = b1[d];
#pragma unroll
        for (int k = 0; k < D; ++k) s = fmaf(xr[k], W1[k * D + d], s);
        ai[(size_t)r * D + d] = s;
    } else if (tl >= 64 && tl < 64 + D) {
        const int d = tl - 64;
        float s = 0.0f;
#pragma unroll
        for (int k = 0; k < D; ++k) s = fmaf(xr[k], W1[(D + k) * D + d], s);
        aj[(size_t)r * D + d] = s;
    }

    if (bid == 0 && t < 64) {
        // A = W2^T: A[m=d, k] = W2[k][d]; lane: m = l&15, k = kt*32 + (l>>4)*8 + e
        const int lr = t & 15, lg = t >> 4;
#pragma unroll
        for (int mt = 0; mt < 3; ++mt)
#pragma unroll
            for (int kt = 0; kt < 2; ++kt) {
                unsigned int u[4];
#pragma unroll
                for (int pe = 0; pe < 4; ++pe) {
                    int k0 = kt * 32 + lg * 8 + pe * 2;
                    int dd = mt * 16 + lr;
                    float v0 = (k0 < D && dd < D) ? W2[k0 * D + dd] : 0.0f;
                    float v1 = (k0 + 1 < D && dd < D) ? W2[(k0 + 1) * D + dd] : 0.0f;
                    u[pe] = pk16(v0, v1);
                }
                w2fT[(mt * 2 + kt) * 64 + t] = make_uint4(u[0], u[1], u[2], u[3]);
            }
    }
}

__global__ __launch_bounds__(256)
__attribute__((amdgpu_waves_per_eu(4)))     // min 4 waves/EU -> VGPR budget <= 128
void pair_kernel(
    const float* __restrict__ ai_g, const float* __restrict__ aj_g,
    const uint4* __restrict__ w2fT, const float* __restrict__ b2,
    float* __restrict__ out) {
    __shared__ float mbuf[224];               // 4 waves x 56 (only LDS use)

    const int t = threadIdx.x;
    const int bid = blockIdx.x;
    const int bb = bid & 1;
    const int i = NN - 1 - (bid >> 1);        // big rows first
    const int w = t >> 6;
    const int l = t & 63;
    const int lr = l & 15;
    const int lg = l >> 4;                    // 0..3

    // W2^T A-fragments (zero rows for k>=40 kill don't-care B slots), pinned
    f16x8 w2t[3][2];
#pragma unroll
    for (int mt = 0; mt < 3; ++mt)
#pragma unroll
        for (int kt = 0; kt < 2; ++kt) {
            w2t[mt][kt] = __builtin_bit_cast(f16x8, w2fT[(mt * 2 + kt) * 64 + l]);
            pin8(w2t[mt][kt]);
        }

    // bias for d = mt*16 + lg*4 + r (0 for d >= 40), pinned
    float bv2[3][4];
#pragma unroll
    for (int mt = 0; mt < 3; ++mt)
#pragma unroll
        for (int r = 0; r < 4; ++r) {
            int d = mt * 16 + lg * 4 + r;
            bv2[mt][r] = (d < D) ? b2[d] : 0.0f;
            pinf(bv2[mt][r]);
        }

    const float* ai_row = ai_g + ((size_t)bb * NN + i) * D;
    float4 air0 = *reinterpret_cast<const float4*>(ai_row + (lg << 3));
    float4 air1 = *reinterpret_cast<const float4*>(ai_row + (lg << 3) + 4);
    float4 ai32 = *reinterpret_cast<const float4*>(ai_row + 32 + ((l >> 5) << 2));
    pin4(air0); pin4(air1); pin4(ai32);

    const float* aj_b = aj_g + (size_t)bb * NN * D;

    // wave-shared online softmax state (mx wave-maxed each window)
    float m_run = 0.0f, l_run = 0.0f;
    float o[3][4];
#pragma unroll
    for (int mt = 0; mt < 3; ++mt)
#pragma unroll
        for (int r = 0; r < 4; ++r) o[mt][r] = 0.0f;

    const int idxA = lr << 2;                 // bpermute byte indices, hoisted

    auto window = [&](int jbase, float4 qa0, float4 qa1, float4 qb0,
                      float4 qb1, float4 qt, bool masked) {
        // tail gelu: k = 32+kk..+3 (kk=(l>>5)*4) of j = jbase+(l&31)
        unsigned int pd0, pd1;
        {
            float g0 = gelu_tanh(ai32.x + qt.x);
            float g1 = gelu_tanh(ai32.y + qt.y);
            float g2 = gelu_tanh(ai32.z + qt.z);
            float g3 = gelu_tanh(ai32.w + qt.w);
            pd0 = pk16(g0, g1);
            pd1 = pk16(g2, g3);
        }
        uint4 tB0, tB1;
        tB0.x = __builtin_amdgcn_ds_bpermute(idxA,       pd0);
        tB0.y = __builtin_amdgcn_ds_bpermute(idxA,       pd1);
        tB0.z = __builtin_amdgcn_ds_bpermute(idxA + 128, pd0);
        tB0.w = __builtin_amdgcn_ds_bpermute(idxA + 128, pd1);
        tB1.x = __builtin_amdgcn_ds_bpermute(idxA + 64,  pd0);
        tB1.y = __builtin_amdgcn_ds_bpermute(idxA + 64,  pd1);
        tB1.z = __builtin_amdgcn_ds_bpermute(idxA + 192, pd0);
        tB1.w = __builtin_amdgcn_ds_bpermute(idxA + 192, pd1);

        f32x4 acc[3][2];
#pragma unroll
        for (int mt = 0; mt < 3; ++mt)
#pragma unroll
            for (int n = 0; n < 2; ++n)
                acc[mt][n] = (f32x4){bv2[mt][0], bv2[mt][1], bv2[mt][2], bv2[mt][3]};
        {
            f16x8 B = frag8(air0, air1, qa0, qa1);
            f16x8 Bt = __builtin_bit_cast(f16x8, tB0);
#pragma unroll
            for (int mt = 0; mt < 3; ++mt) {
                acc[mt][0] = __builtin_amdgcn_mfma_f32_16x16x32_f16(
                    w2t[mt][0], B, acc[mt][0], 0, 0, 0);
                acc[mt][0] = __builtin_amdgcn_mfma_f32_16x16x32_f16(
                    w2t[mt][1], Bt, acc[mt][0], 0, 0, 0);
            }
        }
        {
            f16x8 B = frag8(air0, air1, qb0, qb1);
            f16x8 Bt = __builtin_bit_cast(f16x8, tB1);
#pragma unroll
            for (int mt = 0; mt < 3; ++mt) {
                acc[mt][1] = __builtin_amdgcn_mfma_f32_16x16x32_f16(
                    w2t[mt][0], B, acc[mt][1], 0, 0, 0);
                acc[mt][1] = __builtin_amdgcn_mfma_f32_16x16x32_f16(
                    w2t[mt][1], Bt, acc[mt][1], 0, 0, 0);
            }
        }

        // ||p|| per j; wave-shared online softmax
        float sv[2];
#pragma unroll
        for (int n = 0; n < 2; ++n) {
            float sq = 0.0f;
#pragma unroll
            for (int mt = 0; mt < 3; ++mt)
#pragma unroll
                for (int r = 0; r < 4; ++r)
                    sq = fmaf(acc[mt][n][r], acc[mt][n][r], sq);
            sq += __shfl_xor(sq, 16);
            sq += __shfl_xor(sq, 32);
            if (masked) {
                int j = jbase + n * 16 + lr;
                sv[n] = (j <= i) ? __builtin_amdgcn_sqrtf(sq) : -1e30f;
            } else {
                sv[n] = __builtin_amdgcn_sqrtf(sq);
            }
        }
        float mx = fmaxf(sv[0], sv[1]);
        mx = fmaxf(mx, __shfl_xor(mx, 1));
        mx = fmaxf(mx, __shfl_xor(mx, 2));
        mx = fmaxf(mx, __shfl_xor(mx, 4));
        mx = fmaxf(mx, __shfl_xor(mx, 8));
        if (mx > m_run) {                      // wave-uniform branch
            float scale = __expf(m_run - mx);
            l_run *= scale;
#pragma unroll
            for (int mt = 0; mt < 3; ++mt)
#pragma unroll
                for (int r = 0; r < 4; ++r) o[mt][r] *= scale;
            m_run = mx;
        }
        float w0 = __expf(sv[0] - m_run);      // masked j -> exactly 0
        float w1 = __expf(sv[1] - m_run);
        l_run += w0 + w1;
#pragma unroll
        for (int mt = 0; mt < 3; ++mt)
#pragma unroll
            for (int r = 0; r < 4; ++r)
                o[mt][r] = fmaf(w0, acc[mt][0][r], fmaf(w1, acc[mt][1][r], o[mt][r]));
    };

    // ---- full windows: no clamps, induction pointers, fixed-offset loads ----
    int jbase = w << 5;
    const float* pA = aj_b + (size_t)(jbase + lr) * D + (lg << 3);
    const float* pT = aj_b + (size_t)(jbase + (l & 31)) * D + 32 + ((l >> 5) << 2);
    for (; jbase + 31 <= i; jbase += 128) {
        float4 qa0 = *reinterpret_cast<const float4*>(pA);
        float4 qa1 = *reinterpret_cast<const float4*>(pA + 4);
        float4 qb0 = *reinterpret_cast<const float4*>(pA + 16 * D);
        float4 qb1 = *reinterpret_cast<const float4*>(pA + 16 * D + 4);
        float4 qt  = *reinterpret_cast<const float4*>(pT);
        pA += 128 * D;
        pT += 128 * D;
        window(jbase, qa0, qa1, qb0, qb1, qt, false);
    }
    // ---- at most one partial window (clamped loads, masked sv) ----
    if (jbase <= i) {
        const int j0 = min(jbase + lr, i);
        const int j1 = min(jbase + 16 + lr, i);
        const int jt = min(jbase + (l & 31), i);
        const float* r0 = aj_b + (size_t)j0 * D + (lg << 3);
        const float* r1 = aj_b + (size_t)j1 * D + (lg << 3);
        float4 qa0 = *reinterpret_cast<const float4*>(r0);
        float4 qa1 = *reinterpret_cast<const float4*>(r0 + 4);
        float4 qb0 = *reinterpret_cast<const float4*>(r1);
        float4 qb1 = *reinterpret_cast<const float4*>(r1 + 4);
        float4 qt  = *reinterpret_cast<const float4*>(
            aj_b + (size_t)jt * D + 32 + ((l >> 5) << 2));
        window(jbase, qa0, qa1, qb0, qb1, qt, true);
    }

    // ---- reduce o over the 16 j-lanes, merge 4 waves ----
#pragma unroll
    for (int mt = 0; mt < 3; ++mt)
#pragma unroll
        for (int r = 0; r < 4; ++r) {
            float v = o[mt][r];
            v += __shfl_xor(v, 1);
            v += __shfl_xor(v, 2);
            v += __shfl_xor(v, 4);
            v += __shfl_xor(v, 8);
            o[mt][r] = v;
        }
    l_run += __shfl_xor(l_run, 1);
    l_run += __shfl_xor(l_run, 2);
    l_run += __shfl_xor(l_run, 4);
    l_run += __shfl_xor(l_run, 8);

    if (lr == 0) {
#pragma unroll
        for (int mt = 0; mt < 3; ++mt)
#pragma unroll
            for (int r = 0; r < 4; ++r) {
                int d = mt * 16 + lg * 4 + r;
                if (d < D) mbuf[w * 56 + d] = o[mt][r];
            }
        if (lg == 0) { mbuf[w * 56 + 48] = l_run; mbuf[w * 56 + 49] = m_run; }
    }
    __syncthreads();
    if (t < D) {
        float Mg = fmaxf(fmaxf(mbuf[49], mbuf[56 + 49]),
                         fmaxf(mbuf[112 + 49], mbuf[168 + 49]));
        float L = 0.0f, val = 0.0f;
#pragma unroll
        for (int ww = 0; ww < 4; ++ww) {
            float c = __expf(mbuf[ww * 56 + 49] - Mg);
            L = fmaf(c, mbuf[ww * 56 + 48], L);
            val = fmaf(c, mbuf[ww * 56 + t], val);
        }
        out[((size_t)bb * NN + i) * D + t] = val / L;
    }
}

extern "C" void kernel_launch(void* const* d_in, const int* in_sizes, int n_in,
                              void* d_out, int out_size, void* d_ws, size_t ws_size,
                              hipStream_t stream) {
    const float* x  = (const float*)d_in[0];
    const float* W1 = (const float*)d_in[1];
    const float* b1 = (const float*)d_in[2];
    const float* W2 = (const float*)d_in[3];
    const float* b2 = (const float*)d_in[4];
    float* out = (float*)d_out;

    float* ai = (float*)d_ws;                          // B*N*D floats
    float* aj = ai + (size_t)BB * NN * D;              // B*N*D floats
    uint4* w2fT = (uint4*)(aj + (size_t)BB * NN * D);  // 6*64 uint4

    precompute_kernel<<<BB * NN / 2, 256, 0, stream>>>(x, W1, b1, W2, ai, aj, w2fT);
    pair_kernel<<<BB * NN, 256, 0, stream>>>(ai, aj, w2fT, b2, out);
}